// Round 9
// baseline (360.187 us; speedup 1.0000x reference)
//
#include <hip/hip_runtime.h>
#include <math.h>

#define LEN   5440
#define NB    2
#define MROWS (NB * LEN)   // 10880
#define DM    256
#define NH    8
#define HD    32
#define NLV   4
#define NPT   4
#define DFFN  1024

typedef __attribute__((ext_vector_type(8))) short bf16x8;
typedef __attribute__((ext_vector_type(4))) short bf16x4;
typedef __attribute__((ext_vector_type(4))) float f32x4;

#define MFMA16 __builtin_amdgcn_mfma_f32_16x16x32_bf16

__device__ __forceinline__ short f2bf(float f) {
    union { float f; unsigned u; } cv; cv.f = f;
    unsigned r = cv.u + 0x7fffu + ((cv.u >> 16) & 1u);   // RNE
    return (short)(r >> 16);
}
__device__ __forceinline__ float bf2f(short s) {
    union { unsigned u; float f; } cv;
    cv.u = ((unsigned)(unsigned short)s) << 16;
    return cv.f;
}

// ---------------------------------------------------------------------------
// One-shot: transpose+convert all 12 weight matrices fp32 [K][N] -> bf16 [N][K].
// Per-layer short offsets: Wv@0 | Woff@65536 | Wa@131072 (contiguous 640 rows,
// K=256, fused qkv), Wo@163840, Wl1@229376, Wl2@491520; layer stride 753664.
// ---------------------------------------------------------------------------
__global__ __launch_bounds__(256) void transpose_convert_all(
    const float* __restrict__ Wv,  const float* __restrict__ Woff,
    const float* __restrict__ Wa,  const float* __restrict__ Wo,
    const float* __restrict__ Wl1, const float* __restrict__ Wl2,
    short* __restrict__ out)
{
    int bx = blockIdx.x;
    int l  = bx / 736;
    int t  = bx % 736;
    const float* src; int K, N; long doff;
    if      (t < 64)  { src = Wv;   K = 256;  N = 256;  doff = 0;      }
    else if (t < 128) { src = Woff; K = 256;  N = 256;  doff = 65536;  t -= 64;  }
    else if (t < 160) { src = Wa;   K = 256;  N = 128;  doff = 131072; t -= 128; }
    else if (t < 224) { src = Wo;   K = 256;  N = 256;  doff = 163840; t -= 160; }
    else if (t < 480) { src = Wl1;  K = 256;  N = 1024; doff = 229376; t -= 224; }
    else              { src = Wl2;  K = 1024; N = 256;  doff = 491520; t -= 480; }
    src += (long)l * K * N;
    short* dst = out + (long)l * 753664 + doff;

    const int ntx = N / 32;
    const int n0 = (t % ntx) * 32, k0 = (t / ntx) * 32;

    __shared__ short T[32][33];
    const int tid = threadIdx.x;
    {
        const int n = tid & 31, kq = tid >> 5;
        #pragma unroll
        for (int i = 0; i < 4; ++i) {
            int k = kq * 4 + i;
            T[n][k] = f2bf(src[(long)(k0 + k) * N + n0 + n]);
        }
    }
    __syncthreads();
    {
        const int k = tid & 31, nq = tid >> 5;
        #pragma unroll
        for (int i = 0; i < 4; ++i) {
            int n = nq * 4 + i;
            dst[(long)(n0 + n) * K + k0 + k] = T[n][k];
        }
    }
}

// ---------------------------------------------------------------------------
// src -> bf16(src), bf16(src+pos)
// ---------------------------------------------------------------------------
__global__ __launch_bounds__(256) void convert_src(
    const float4* __restrict__ s4, const float4* __restrict__ p4,
    bf16x4* __restrict__ curb, bf16x4* __restrict__ qb)
{
    const int i = blockIdx.x * 256 + threadIdx.x;
    float4 s = s4[i], p = p4[i];
    bf16x4 c, q;
    c[0] = f2bf(s.x); c[1] = f2bf(s.y); c[2] = f2bf(s.z); c[3] = f2bf(s.w);
    q[0] = f2bf(s.x + p.x); q[1] = f2bf(s.y + p.y);
    q[2] = f2bf(s.z + p.z); q[3] = f2bf(s.w + p.w);
    curb[i] = c; qb[i] = q;
}

// ---------------------------------------------------------------------------
// MFMA bf16 GEMM, 128 x BN tile, BK=32, padded LDS (stride 40 shorts),
// explicit global->reg prefetch. OMODE: 0 f32 row-major, 1 bf16 row-major,
// 2 bf16 into V planes (n*8+h, len, 32).
// ---------------------------------------------------------------------------
template <int BN, int RELU, int OMODE>
__device__ __forceinline__ void gemm_core128(
    short* As, short* Bs,
    const short* __restrict__ A, const short* __restrict__ Wt,
    const float* __restrict__ bias, float* __restrict__ Cf,
    short* __restrict__ Cb,
    int ldc, int m0, int wrow0, int ccol0, int K)
{
    constexpr int NF = BN / 32;
    constexpr int NBJ = BN / 64;
    const int t    = threadIdx.x;
    const int wave = t >> 6, lane = t & 63;
    const int wm   = (wave & 1) * 64;
    const int wn   = (wave >> 1) * (BN / 2);
    const int lm   = lane & 15;
    const int chkg = lane >> 4;
    const int srow = t >> 2;
    const int sc   = t & 3;

    f32x4 acc[4][NF] = {};
    bf16x8 ar[2], br[NBJ];

    #pragma unroll
    for (int j = 0; j < 2; ++j)
        ar[j] = *(const bf16x8*)(A + (long)(m0 + srow + 64 * j) * K + sc * 8);
    #pragma unroll
    for (int j = 0; j < NBJ; ++j)
        br[j] = *(const bf16x8*)(Wt + (long)(wrow0 + srow + 64 * j) * K + sc * 8);

    for (int k0 = 0; k0 < K; k0 += 32) {
        __syncthreads();
        #pragma unroll
        for (int j = 0; j < 2; ++j)
            *(bf16x8*)(&As[(srow + 64 * j) * 40 + sc * 8]) = ar[j];
        #pragma unroll
        for (int j = 0; j < NBJ; ++j)
            *(bf16x8*)(&Bs[(srow + 64 * j) * 40 + sc * 8]) = br[j];
        __syncthreads();

        if (k0 + 32 < K) {
            #pragma unroll
            for (int j = 0; j < 2; ++j)
                ar[j] = *(const bf16x8*)(A + (long)(m0 + srow + 64 * j) * K + k0 + 32 + sc * 8);
            #pragma unroll
            for (int j = 0; j < NBJ; ++j)
                br[j] = *(const bf16x8*)(Wt + (long)(wrow0 + srow + 64 * j) * K + k0 + 32 + sc * 8);
        }

        bf16x8 af[4], bfv[NF];
        #pragma unroll
        for (int s = 0; s < 4; ++s)
            af[s] = *(const bf16x8*)(&As[(wm + s * 16 + lm) * 40 + chkg * 8]);
        #pragma unroll
        for (int u = 0; u < NF; ++u)
            bfv[u] = *(const bf16x8*)(&Bs[(wn + u * 16 + lm) * 40 + chkg * 8]);
        #pragma unroll
        for (int s = 0; s < 4; ++s)
            #pragma unroll
            for (int u = 0; u < NF; ++u)
                acc[s][u] = MFMA16(af[s], bfv[u], acc[s][u], 0, 0, 0);
    }

    const int col = lane & 15;
    const int rq  = (lane >> 4) * 4;
    #pragma unroll
    for (int s = 0; s < 4; ++s) {
        #pragma unroll
        for (int u = 0; u < NF; ++u) {
            const int gn = ccol0 + wn + u * 16 + col;
            const float bb = bias[gn];
            #pragma unroll
            for (int r = 0; r < 4; ++r) {
                const int gm = m0 + wm + s * 16 + rq + r;
                float v = acc[s][u][r] + bb;
                if (RELU) v = fmaxf(v, 0.f);
                if (OMODE == 0) {
                    Cf[(long)gm * ldc + gn] = v;
                } else if (OMODE == 1) {
                    Cb[(long)gm * ldc + gn] = f2bf(v);
                } else {
                    const int n   = gm / LEN;
                    const int pix = gm - n * LEN;
                    const int h   = gn >> 5, d = gn & 31;
                    Cb[((long)(n * NH + h) * LEN + pix) * 32 + d] = f2bf(v);
                }
            }
        }
    }
}

// Fused query-side GEMM: [Vb | OFF | AW] over N=640 (Wv|Woff|Wa rows contiguous).
__global__ __launch_bounds__(256) void gemm_qkv128(
    const short* __restrict__ curb, const short* __restrict__ qb,
    const short* __restrict__ Wt, const float* __restrict__ bv,
    const float* __restrict__ boff, const float* __restrict__ ba,
    short* __restrict__ Vb, float* __restrict__ OFF, float* __restrict__ AW)
{
    __shared__ __align__(16) short As[128 * 40];
    __shared__ __align__(16) short Bs[128 * 40];
    const int n0 = blockIdx.x * 128;   // 0,128,256,384,512
    if (n0 < 256) {
        gemm_core128<128, 0, 2>(As, Bs, curb, Wt, bv, (float*)nullptr, Vb,
                                256, blockIdx.y * 128, n0, n0, 256);
    } else if (n0 < 512) {
        gemm_core128<128, 0, 0>(As, Bs, qb, Wt, boff, OFF, (short*)nullptr,
                                256, blockIdx.y * 128, n0, n0 - 256, 256);
    } else {
        gemm_core128<128, 0, 0>(As, Bs, qb, Wt, ba, AW, (short*)nullptr,
                                128, blockIdx.y * 128, n0, n0 - 512, 256);
    }
}

// ---------------------------------------------------------------------------
// Fused GEMM + residual + LayerNorm (K=256 only: Wo-proj + LN1).
// M-tile 64, N=256, BK=64 (unchanged from R8).
// ---------------------------------------------------------------------------
template <int K>
__global__ __launch_bounds__(256) void gemm_ln(
    const short* __restrict__ A, const short* __restrict__ Wt,
    const float* __restrict__ bias, const float* __restrict__ resid,
    const float* __restrict__ g, const float* __restrict__ be,
    float* __restrict__ outf, short* __restrict__ outb,
    short* __restrict__ outq, const float* __restrict__ pos)
{
    __shared__ __align__(16) short As[64 * 72];
    __shared__ __align__(16) short Bs[256 * 72];
    __shared__ float red[4][64][2];

    const int t    = threadIdx.x;
    const int wave = t >> 6, lane = t & 63;
    const int wn   = wave * 64;
    const int lm   = lane & 15;
    const int chkg = lane >> 4;
    const int srow = t >> 2;          // 0..63
    const int sc   = t & 3;
    const int m0   = blockIdx.x * 64;

    f32x4 acc[4][4] = {};
    bf16x8 ar[2], br[8];

    #pragma unroll
    for (int c = 0; c < 2; ++c)
        ar[c] = *(const bf16x8*)(A + (long)(m0 + srow) * K + c * 32 + sc * 8);
    #pragma unroll
    for (int j = 0; j < 4; ++j)
        #pragma unroll
        for (int c = 0; c < 2; ++c)
            br[j * 2 + c] = *(const bf16x8*)(Wt + (long)(srow + 64 * j) * K + c * 32 + sc * 8);

    for (int k0 = 0; k0 < K; k0 += 64) {
        __syncthreads();
        #pragma unroll
        for (int c = 0; c < 2; ++c)
            *(bf16x8*)(&As[srow * 72 + c * 32 + sc * 8]) = ar[c];
        #pragma unroll
        for (int j = 0; j < 4; ++j)
            #pragma unroll
            for (int c = 0; c < 2; ++c)
                *(bf16x8*)(&Bs[(srow + 64 * j) * 72 + c * 32 + sc * 8]) = br[j * 2 + c];
        __syncthreads();

        if (k0 + 64 < K) {
            #pragma unroll
            for (int c = 0; c < 2; ++c)
                ar[c] = *(const bf16x8*)(A + (long)(m0 + srow) * K + k0 + 64 + c * 32 + sc * 8);
            #pragma unroll
            for (int j = 0; j < 4; ++j)
                #pragma unroll
                for (int c = 0; c < 2; ++c)
                    br[j * 2 + c] = *(const bf16x8*)(Wt + (long)(srow + 64 * j) * K + k0 + 64 + c * 32 + sc * 8);
        }

        #pragma unroll
        for (int kk = 0; kk < 2; ++kk) {
            bf16x8 af[4], bfv[4];
            #pragma unroll
            for (int s = 0; s < 4; ++s)
                af[s] = *(const bf16x8*)(&As[(s * 16 + lm) * 72 + kk * 32 + chkg * 8]);
            #pragma unroll
            for (int u = 0; u < 4; ++u)
                bfv[u] = *(const bf16x8*)(&Bs[(wn + u * 16 + lm) * 72 + kk * 32 + chkg * 8]);
            #pragma unroll
            for (int s = 0; s < 4; ++s)
                #pragma unroll
                for (int u = 0; u < 4; ++u)
                    acc[s][u] = MFMA16(af[s], bfv[u], acc[s][u], 0, 0, 0);
        }
    }

    const int rq = (lane >> 4) * 4;
    #pragma unroll
    for (int u = 0; u < 4; ++u) {
        const int gn = wn + u * 16 + lm;
        const float bb = bias[gn];
        #pragma unroll
        for (int s = 0; s < 4; ++s)
            #pragma unroll
            for (int r = 0; r < 4; ++r)
                acc[s][u][r] += bb + resid[(long)(m0 + s * 16 + rq + r) * DM + gn];
    }

    float ps[4][4], p2[4][4];
    #pragma unroll
    for (int s = 0; s < 4; ++s)
        #pragma unroll
        for (int r = 0; r < 4; ++r) {
            float sm = 0.f, s2 = 0.f;
            #pragma unroll
            for (int u = 0; u < 4; ++u) {
                const float v = acc[s][u][r];
                sm += v; s2 += v * v;
            }
            ps[s][r] = sm; p2[s][r] = s2;
        }
    #pragma unroll
    for (int o = 1; o < 16; o <<= 1)
        #pragma unroll
        for (int s = 0; s < 4; ++s)
            #pragma unroll
            for (int r = 0; r < 4; ++r) {
                ps[s][r] += __shfl_xor(ps[s][r], o, 64);
                p2[s][r] += __shfl_xor(p2[s][r], o, 64);
            }
    if (lm == 0) {
        #pragma unroll
        for (int s = 0; s < 4; ++s)
            #pragma unroll
            for (int r = 0; r < 4; ++r) {
                red[wave][s * 16 + rq + r][0] = ps[s][r];
                red[wave][s * 16 + rq + r][1] = p2[s][r];
            }
    }
    __syncthreads();

    float mean[4][4], rstd[4][4];
    #pragma unroll
    for (int s = 0; s < 4; ++s)
        #pragma unroll
        for (int r = 0; r < 4; ++r) {
            const int row = s * 16 + rq + r;
            const float ts = red[0][row][0] + red[1][row][0] + red[2][row][0] + red[3][row][0];
            const float t2 = red[0][row][1] + red[1][row][1] + red[2][row][1] + red[3][row][1];
            const float m = ts * (1.f / DM);
            mean[s][r] = m;
            rstd[s][r] = rsqrtf(t2 * (1.f / DM) - m * m + 1e-5f);
        }

    #pragma unroll
    for (int u = 0; u < 4; ++u) {
        const int gn = wn + u * 16 + lm;
        const float gg = g[gn], bbe = be[gn];
        #pragma unroll
        for (int s = 0; s < 4; ++s)
            #pragma unroll
            for (int r = 0; r < 4; ++r) {
                const long gm = m0 + s * 16 + rq + r;
                const float o = (acc[s][u][r] - mean[s][r]) * rstd[s][r] * gg + bbe;
                outf[gm * DM + gn] = o;
                if (outb) outb[gm * DM + gn] = f2bf(o);
                if (outq) outq[gm * DM + gn] = f2bf(o + pos[gm * DM + gn]);
            }
    }
}

// ---------------------------------------------------------------------------
// Fully-fused FFN: out = LN(resid + relu(X@Wl1+bl1)@Wl2 + bl2).
// M-tile 32 (grid 340). Hidden tile lives in LDS (two 512-col halves) —
// never touches HBM. B-fragments gathered directly from L2-resident weights
// (no B staging, no K-loop barriers). Phase 1: wave w computes hidden cols
// [hh*512+w*128, +128). Phase 2: wave w computes out cols [w*64, +64),
// A-frags from Hs. Epilogue: residual + LN (xor-shuffle + 4-wave combine).
// ---------------------------------------------------------------------------
__global__ __launch_bounds__(256) void ffn_fused(
    const short* __restrict__ XAb,   // (MROWS, 256) bf16
    const short* __restrict__ Wl1t,  // (1024, 256) bf16
    const short* __restrict__ Wl2t,  // (256, 1024) bf16
    const float* __restrict__ bl1, const float* __restrict__ bl2,
    const float* __restrict__ resid, // XA f32
    const float* __restrict__ g, const float* __restrict__ be,
    float* __restrict__ outf, short* __restrict__ outb,
    short* __restrict__ outq, const float* __restrict__ pos)
{
    __shared__ __align__(16) short Xs[32 * 264];   // X tile, stride 264
    __shared__ __align__(16) short Hs[32 * 520];   // hidden half, stride 520
    __shared__ float red[4][32][2];

    const int t    = threadIdx.x;
    const int wave = t >> 6, lane = t & 63;
    const int lm   = lane & 15;
    const int chkg = lane >> 4;
    const int m0   = blockIdx.x * 32;

    // ---- load X tile (32 x 256 bf16, contiguous 16 KB) ----
    {
        const bf16x8* src = (const bf16x8*)(XAb + (long)m0 * 256);
        #pragma unroll
        for (int j = 0; j < 4; ++j) {
            const int linear = t + 256 * j;          // 0..1023
            const int m = linear >> 5, kv = (linear & 31) * 8;
            *(bf16x8*)(&Xs[m * 264 + kv]) = src[linear];
        }
    }

    f32x4 acc[2][4] = {};   // phase-2 accumulators, persist across halves

    for (int hh = 0; hh < 2; ++hh) {
        __syncthreads();    // Xs ready (iter 0) / Hs reads of prev half done

        // ---- phase 1: hidden half hh ----
        bf16x8 af1[2][8];
        #pragma unroll
        for (int s = 0; s < 2; ++s)
            #pragma unroll
            for (int k0 = 0; k0 < 8; ++k0)
                af1[s][k0] = *(const bf16x8*)(&Xs[(s * 16 + lm) * 264 + k0 * 32 + chkg * 8]);

        const int hwb = hh * 512 + wave * 128;     // global hidden col base
        #pragma unroll
        for (int nc = 0; nc < 8; ++nc) {
            f32x4 a1[2] = {};
            const short* wrow = Wl1t + (long)(hwb + nc * 16 + lm) * 256 + chkg * 8;
            #pragma unroll
            for (int k0 = 0; k0 < 8; ++k0) {
                const bf16x8 bf = *(const bf16x8*)(wrow + k0 * 32);
                a1[0] = MFMA16(af1[0][k0], bf, a1[0], 0, 0, 0);
                a1[1] = MFMA16(af1[1][k0], bf, a1[1], 0, 0, 0);
            }
            const int hcol_l = wave * 128 + nc * 16 + lm;   // col in Hs [0,512)
            const float bb = bl1[hwb + nc * 16 + lm];
            #pragma unroll
            for (int s = 0; s < 2; ++s)
                #pragma unroll
                for (int r = 0; r < 4; ++r) {
                    const float v = fmaxf(a1[s][r] + bb, 0.f);
                    Hs[(s * 16 + chkg * 4 + r) * 520 + hcol_l] = f2bf(v);
                }
        }
        __syncthreads();

        // ---- phase 2: acc += H_half @ Wl2t[:, half] ----
        const short* w2base = Wl2t + (long)(wave * 64 + lm) * 1024 + hh * 512 + chkg * 8;
        #pragma unroll 4
        for (int k0 = 0; k0 < 16; ++k0) {
            bf16x8 af[2];
            af[0] = *(const bf16x8*)(&Hs[lm * 520        + k0 * 32 + chkg * 8]);
            af[1] = *(const bf16x8*)(&Hs[(16 + lm) * 520 + k0 * 32 + chkg * 8]);
            #pragma unroll
            for (int u = 0; u < 4; ++u) {
                const bf16x8 bf = *(const bf16x8*)(w2base + (long)u * 16 * 1024 + k0 * 32);
                acc[0][u] = MFMA16(af[0], bf, acc[0][u], 0, 0, 0);
                acc[1][u] = MFMA16(af[1], bf, acc[1][u], 0, 0, 0);
            }
        }
    }

    // ---- epilogue: bias + residual + LayerNorm over 256 cols ----
    const int rq = chkg * 4;
    #pragma unroll
    for (int u = 0; u < 4; ++u) {
        const int gn = wave * 64 + u * 16 + lm;
        const float bb = bl2[gn];
        #pragma unroll
        for (int s = 0; s < 2; ++s)
            #pragma unroll
            for (int r = 0; r < 4; ++r)
                acc[s][u][r] += bb + resid[(long)(m0 + s * 16 + rq + r) * DM + gn];
    }

    float ps[2][4], p2[2][4];
    #pragma unroll
    for (int s = 0; s < 2; ++s)
        #pragma unroll
        for (int r = 0; r < 4; ++r) {
            float sm = 0.f, s2 = 0.f;
            #pragma unroll
            for (int u = 0; u < 4; ++u) {
                const float v = acc[s][u][r];
                sm += v; s2 += v * v;
            }
            ps[s][r] = sm; p2[s][r] = s2;
        }
    #pragma unroll
    for (int o = 1; o < 16; o <<= 1)
        #pragma unroll
        for (int s = 0; s < 2; ++s)
            #pragma unroll
            for (int r = 0; r < 4; ++r) {
                ps[s][r] += __shfl_xor(ps[s][r], o, 64);
                p2[s][r] += __shfl_xor(p2[s][r], o, 64);
            }
    if (lm == 0) {
        #pragma unroll
        for (int s = 0; s < 2; ++s)
            #pragma unroll
            for (int r = 0; r < 4; ++r) {
                red[wave][s * 16 + rq + r][0] = ps[s][r];
                red[wave][s * 16 + rq + r][1] = p2[s][r];
            }
    }
    __syncthreads();

    float mean[2][4], rstd[2][4];
    #pragma unroll
    for (int s = 0; s < 2; ++s)
        #pragma unroll
        for (int r = 0; r < 4; ++r) {
            const int row = s * 16 + rq + r;
            const float ts = red[0][row][0] + red[1][row][0] + red[2][row][0] + red[3][row][0];
            const float t2 = red[0][row][1] + red[1][row][1] + red[2][row][1] + red[3][row][1];
            const float m = ts * (1.f / DM);
            mean[s][r] = m;
            rstd[s][r] = rsqrtf(t2 * (1.f / DM) - m * m + 1e-5f);
        }

    #pragma unroll
    for (int u = 0; u < 4; ++u) {
        const int gn = wave * 64 + u * 16 + lm;
        const float gg = g[gn], bbe = be[gn];
        #pragma unroll
        for (int s = 0; s < 2; ++s)
            #pragma unroll
            for (int r = 0; r < 4; ++r) {
                const long gm = m0 + s * 16 + rq + r;
                const float o = (acc[s][u][r] - mean[s][r]) * rstd[s][r] * gg + bbe;
                outf[gm * DM + gn] = o;
                if (outb) outb[gm * DM + gn] = f2bf(o);
                if (outq) outq[gm * DM + gn] = f2bf(o + pos[gm * DM + gn]);
            }
    }
}

// ---------------------------------------------------------------------------
// Deformable attention sampling v3 (unchanged).
// ---------------------------------------------------------------------------
__global__ __launch_bounds__(256) void deform_attn_v3(
    const short* __restrict__ Vb,    // (NB*NH, LEN, 32) bf16
    const float* __restrict__ OFF,   // (MROWS, 256)
    const float* __restrict__ AW,    // (MROWS, 128)
    const float* __restrict__ vr,    // (NB, NLV, 2)
    bf16x4* __restrict__ ATTb)       // (MROWS, 64) bf16x4
{
    const int starts[5] = {0, 4096, 5120, 5376, 5440};
    const int dims[4]   = {64, 32, 16, 8};

    const int wave = threadIdx.x >> 6;
    const int lane = threadIdx.x & 63;
    const int h    = lane >> 3;
    const int d4   = lane & 7;

    const int gq = blockIdx.x * 4 + wave;
    const int n  = gq / LEN;
    const int q  = gq % LEN;

    int lq = 3;
    if (q < 4096) lq = 0; else if (q < 5120) lq = 1; else if (q < 5376) lq = 2;
    const int r  = q - starts[lq];
    const int Wq = dims[lq];
    const int gy = r / Wq, gx = r % Wq;
    const float vrxq = vr[(n * NLV + lq) * 2 + 0];
    const float vryq = vr[(n * NLV + lq) * 2 + 1];
    const float rx = (gx + 0.5f) / (vrxq * Wq);
    const float ry = (gy + 0.5f) / (vryq * Wq);

    const long row = (long)n * LEN + q;

    const float* awp = AW + row * 128 + h * 16;
    float a[16];
    float mx = -1e30f;
    #pragma unroll
    for (int i = 0; i < 16; ++i) { a[i] = awp[i]; mx = fmaxf(mx, a[i]); }
    float s = 0.f;
    #pragma unroll
    for (int i = 0; i < 16; ++i) { a[i] = __expf(a[i] - mx); s += a[i]; }
    const float inv = 1.f / s;

    const float* offp = OFF + row * 256 + h * 32;

    float4 acc = {0.f, 0.f, 0.f, 0.f};
    #pragma unroll
    for (int lvl = 0; lvl < NLV; ++lvl) {
        const int Hl = dims[lvl];
        const int Wl = Hl;
        const float fW = (float)Wl;
        const int sb = starts[lvl];
        const float lx = rx * vr[(n * NLV + lvl) * 2 + 0];
        const float ly = ry * vr[(n * NLV + lvl) * 2 + 1];
        const short* vb = Vb + ((long)(n * NH + h) * LEN + sb) * 32 + d4 * 4;
        #pragma unroll
        for (int p = 0; p < NPT; ++p) {
            const float ox = offp[lvl * 8 + p * 2 + 0];
            const float oy = offp[lvl * 8 + p * 2 + 1];
            const float x = fmaf(lx, fW, ox) - 0.5f;
            const float y = fmaf(ly, fW, oy) - 0.5f;
            const float x0f = floorf(x), y0f = floorf(y);
            const int ix0 = (int)x0f, iy0 = (int)y0f;
            const float wx1 = x - x0f, wy1 = y - y0f;
            const float wx0 = 1.f - wx1, wy0 = 1.f - wy1;

            const bool vx0 = (ix0 >= 0)     && (ix0 < Wl);
            const bool vx1 = (ix0 + 1 >= 0) && (ix0 + 1 < Wl);
            const bool vy0 = (iy0 >= 0)     && (iy0 < Hl);
            const bool vy1 = (iy0 + 1 >= 0) && (iy0 + 1 < Hl);
            const int cx0 = min(max(ix0, 0), Wl - 1);
            const int cx1 = min(max(ix0 + 1, 0), Wl - 1);
            const int cy0 = min(max(iy0, 0), Hl - 1);
            const int cy1 = min(max(iy0 + 1, 0), Hl - 1);

            const float w00 = (vx0 && vy0) ? wx0 * wy0 : 0.f;
            const float w10 = (vx1 && vy0) ? wx1 * wy0 : 0.f;
            const float w01 = (vx0 && vy1) ? wx0 * wy1 : 0.f;
            const float w11 = (vx1 && vy1) ? wx1 * wy1 : 0.f;

            const bf16x4 g00 = *(const bf16x4*)(vb + (long)(cy0 * Wl + cx0) * 32);
            const bf16x4 g10 = *(const bf16x4*)(vb + (long)(cy0 * Wl + cx1) * 32);
            const bf16x4 g01 = *(const bf16x4*)(vb + (long)(cy1 * Wl + cx0) * 32);
            const bf16x4 g11 = *(const bf16x4*)(vb + (long)(cy1 * Wl + cx1) * 32);

            const float awv = a[lvl * 4 + p] * inv;
            #pragma unroll
            for (int e = 0; e < 4; ++e) {
                float sv = w00 * bf2f(g00[e]) + w10 * bf2f(g10[e])
                         + w01 * bf2f(g01[e]) + w11 * bf2f(g11[e]);
                (&acc.x)[e] += awv * sv;
            }
        }
    }
    bf16x4 ob;
    ob[0] = f2bf(acc.x); ob[1] = f2bf(acc.y);
    ob[2] = f2bf(acc.z); ob[3] = f2bf(acc.w);
    ATTb[row * 64 + h * 8 + d4] = ob;
}

// ---------------------------------------------------------------------------
extern "C" void kernel_launch(void* const* d_in, const int* in_sizes, int n_in,
                              void* d_out, int out_size, void* d_ws, size_t ws_size,
                              hipStream_t stream)
{
    const float* src = (const float*)d_in[0];
    const float* pos = (const float*)d_in[1];
    const float* vr  = (const float*)d_in[2];
    const float* Wv_   = (const float*)d_in[3];
    const float* bv_   = (const float*)d_in[4];
    const float* Woff_ = (const float*)d_in[5];
    const float* boff_ = (const float*)d_in[6];
    const float* Wa_   = (const float*)d_in[7];
    const float* ba_   = (const float*)d_in[8];
    const float* Wo_   = (const float*)d_in[9];
    const float* bo_   = (const float*)d_in[10];
    const float* g1_   = (const float*)d_in[11];
    const float* be1_  = (const float*)d_in[12];
    const float* Wl1_  = (const float*)d_in[13];
    const float* bl1_  = (const float*)d_in[14];
    const float* Wl2_  = (const float*)d_in[15];
    const float* bl2_  = (const float*)d_in[16];
    const float* g2_   = (const float*)d_in[17];
    const float* be2_  = (const float*)d_in[18];

    const long SZ = (long)MROWS * DM;        // 2,785,280 elements
    float* ws = (float*)d_ws;
    float* OFF  = ws;                         // f32 M x 256
    float* AW   = OFF + SZ;                   // f32 M x 128
    float* XA   = AW  + (long)MROWS * 128;    // f32 M x 256 (LN1 out)
    float* XB   = XA  + SZ;                   // f32 M x 256 (LN2 out, layer0)
    short* Vb   = (short*)(XB + SZ);          // bf16 (NB*NH, LEN, 32)
    short* curb = Vb   + SZ;                  // bf16 M x 256
    short* qb   = curb + SZ;                  // bf16 M x 256
    short* ATTb = qb   + SZ;                  // bf16 M x 256
    short* XAb  = ATTb + SZ;                  // bf16 M x 256
    short* Wt   = XAb  + SZ;                  // 2 x 753664 bf16 weights

    const dim3 blk(256);
    const int GYM = MROWS / 128;              // 85
    const int GLN = MROWS / 64;               // 170
    const int GFF = MROWS / 32;               // 340

    hipLaunchKernelGGL(transpose_convert_all, dim3(1472), blk, 0, stream,
                       Wv_, Woff_, Wa_, Wo_, Wl1_, Wl2_, Wt);
    hipLaunchKernelGGL(convert_src, dim3(SZ / 4 / 256), blk, 0, stream,
                       (const float4*)src, (const float4*)pos,
                       (bf16x4*)curb, (bf16x4*)qb);

    const float* cur = src;
    for (int l = 0; l < 2; ++l) {
        const short* Wbase = Wt + (long)l * 753664;
        const float* bv   = bv_   + (long)l * DM;
        const float* boff = boff_ + (long)l * 256;
        const float* ba   = ba_   + (long)l * 128;
        const float* bo   = bo_   + (long)l * DM;
        const float* g1   = g1_   + (long)l * DM;
        const float* be1  = be1_  + (long)l * DM;
        const float* bl1  = bl1_  + (long)l * DFFN;
        const float* bl2  = bl2_  + (long)l * DM;
        const float* g2   = g2_   + (long)l * DM;
        const float* be2  = be2_  + (long)l * DM;

        // [Vb | OFF | AW] = [curb | qb] @ [Wv|Woff|Wa]   (BN=128, 5x85)
        hipLaunchKernelGGL(gemm_qkv128, dim3(5, GYM), blk, 0, stream,
                           curb, qb, Wbase, bv, boff, ba, Vb, OFF, AW);
        hipLaunchKernelGGL(deform_attn_v3, dim3(MROWS / 4), blk, 0, stream,
                           Vb, OFF, AW, vr, (bf16x4*)ATTb);
        // XA = LN(cur + ATT@Wo + bo); also bf16 XAb for the FFN
        hipLaunchKernelGGL((gemm_ln<256>), dim3(GLN), blk, 0, stream,
                           ATTb, Wbase + 163840, bo, cur, g1, be1,
                           XA, XAb, (short*)nullptr, (const float*)nullptr);
        // out = LN(XA + relu(XAb@Wl1+bl1)@Wl2 + bl2)  — fully fused FFN
        if (l == 0) {
            hipLaunchKernelGGL(ffn_fused, dim3(GFF), blk, 0, stream,
                               XAb, Wbase + 229376, Wbase + 491520, bl1, bl2,
                               XA, g2, be2, XB, curb, qb, pos);
            cur = XB;
        } else {
            hipLaunchKernelGGL(ffn_fused, dim3(GFF), blk, 0, stream,
                               XAb, Wbase + 229376, Wbase + 491520, bl1, bl2,
                               XA, g2, be2, (float*)d_out, (short*)nullptr,
                               (short*)nullptr, (const float*)nullptr);
        }
    }
}

// Round 10
// 308.566 us; speedup vs baseline: 1.1673x; 1.1673x over previous
//
#include <hip/hip_runtime.h>
#include <math.h>

#define LEN   5440
#define NB    2
#define MROWS (NB * LEN)   // 10880
#define DM    256
#define NH    8
#define HD    32
#define NLV   4
#define NPT   4
#define DFFN  1024

typedef __attribute__((ext_vector_type(8))) short bf16x8;
typedef __attribute__((ext_vector_type(4))) short bf16x4;
typedef __attribute__((ext_vector_type(4))) float f32x4;

#define MFMA16 __builtin_amdgcn_mfma_f32_16x16x32_bf16

__device__ __forceinline__ short f2bf(float f) {
    union { float f; unsigned u; } cv; cv.f = f;
    unsigned r = cv.u + 0x7fffu + ((cv.u >> 16) & 1u);   // RNE
    return (short)(r >> 16);
}
__device__ __forceinline__ float bf2f(short s) {
    union { unsigned u; float f; } cv;
    cv.u = ((unsigned)(unsigned short)s) << 16;
    return cv.f;
}

// ---------------------------------------------------------------------------
// One-shot: transpose+convert all 12 weight matrices fp32 [K][N] -> bf16 [N][K].
// Per-layer short offsets: Wv@0 | Woff@65536 | Wa@131072 (contiguous 640 rows,
// K=256, fused qkv), Wo@163840, Wl1@229376, Wl2@491520; layer stride 753664.
// ---------------------------------------------------------------------------
__global__ __launch_bounds__(256) void transpose_convert_all(
    const float* __restrict__ Wv,  const float* __restrict__ Woff,
    const float* __restrict__ Wa,  const float* __restrict__ Wo,
    const float* __restrict__ Wl1, const float* __restrict__ Wl2,
    short* __restrict__ out)
{
    int bx = blockIdx.x;
    int l  = bx / 736;
    int t  = bx % 736;
    const float* src; int K, N; long doff;
    if      (t < 64)  { src = Wv;   K = 256;  N = 256;  doff = 0;      }
    else if (t < 128) { src = Woff; K = 256;  N = 256;  doff = 65536;  t -= 64;  }
    else if (t < 160) { src = Wa;   K = 256;  N = 128;  doff = 131072; t -= 128; }
    else if (t < 224) { src = Wo;   K = 256;  N = 256;  doff = 163840; t -= 160; }
    else if (t < 480) { src = Wl1;  K = 256;  N = 1024; doff = 229376; t -= 224; }
    else              { src = Wl2;  K = 1024; N = 256;  doff = 491520; t -= 480; }
    src += (long)l * K * N;
    short* dst = out + (long)l * 753664 + doff;

    const int ntx = N / 32;
    const int n0 = (t % ntx) * 32, k0 = (t / ntx) * 32;

    __shared__ short T[32][33];
    const int tid = threadIdx.x;
    {
        const int n = tid & 31, kq = tid >> 5;
        #pragma unroll
        for (int i = 0; i < 4; ++i) {
            int k = kq * 4 + i;
            T[n][k] = f2bf(src[(long)(k0 + k) * N + n0 + n]);
        }
    }
    __syncthreads();
    {
        const int k = tid & 31, nq = tid >> 5;
        #pragma unroll
        for (int i = 0; i < 4; ++i) {
            int n = nq * 4 + i;
            dst[(long)(n0 + n) * K + k0 + k] = T[n][k];
        }
    }
}

// ---------------------------------------------------------------------------
// src -> bf16(src), bf16(src+pos)
// ---------------------------------------------------------------------------
__global__ __launch_bounds__(256) void convert_src(
    const float4* __restrict__ s4, const float4* __restrict__ p4,
    bf16x4* __restrict__ curb, bf16x4* __restrict__ qb)
{
    const int i = blockIdx.x * 256 + threadIdx.x;
    float4 s = s4[i], p = p4[i];
    bf16x4 c, q;
    c[0] = f2bf(s.x); c[1] = f2bf(s.y); c[2] = f2bf(s.z); c[3] = f2bf(s.w);
    q[0] = f2bf(s.x + p.x); q[1] = f2bf(s.y + p.y);
    q[2] = f2bf(s.z + p.z); q[3] = f2bf(s.w + p.w);
    curb[i] = c; qb[i] = q;
}

// ---------------------------------------------------------------------------
// MFMA bf16 GEMM, 128 x BN tile, BK=32, padded LDS (stride 40 shorts),
// explicit global->reg prefetch. OMODE: 0 f32 row-major, 1 bf16 row-major,
// 2 bf16 into V planes (n*8+h, len, 32).
// ---------------------------------------------------------------------------
template <int BN, int RELU, int OMODE>
__device__ __forceinline__ void gemm_core128(
    short* As, short* Bs,
    const short* __restrict__ A, const short* __restrict__ Wt,
    const float* __restrict__ bias, float* __restrict__ Cf,
    short* __restrict__ Cb,
    int ldc, int m0, int wrow0, int ccol0, int K)
{
    constexpr int NF = BN / 32;
    constexpr int NBJ = BN / 64;
    const int t    = threadIdx.x;
    const int wave = t >> 6, lane = t & 63;
    const int wm   = (wave & 1) * 64;
    const int wn   = (wave >> 1) * (BN / 2);
    const int lm   = lane & 15;
    const int chkg = lane >> 4;
    const int srow = t >> 2;
    const int sc   = t & 3;

    f32x4 acc[4][NF] = {};
    bf16x8 ar[2], br[NBJ];

    #pragma unroll
    for (int j = 0; j < 2; ++j)
        ar[j] = *(const bf16x8*)(A + (long)(m0 + srow + 64 * j) * K + sc * 8);
    #pragma unroll
    for (int j = 0; j < NBJ; ++j)
        br[j] = *(const bf16x8*)(Wt + (long)(wrow0 + srow + 64 * j) * K + sc * 8);

    for (int k0 = 0; k0 < K; k0 += 32) {
        __syncthreads();
        #pragma unroll
        for (int j = 0; j < 2; ++j)
            *(bf16x8*)(&As[(srow + 64 * j) * 40 + sc * 8]) = ar[j];
        #pragma unroll
        for (int j = 0; j < NBJ; ++j)
            *(bf16x8*)(&Bs[(srow + 64 * j) * 40 + sc * 8]) = br[j];
        __syncthreads();

        if (k0 + 32 < K) {
            #pragma unroll
            for (int j = 0; j < 2; ++j)
                ar[j] = *(const bf16x8*)(A + (long)(m0 + srow + 64 * j) * K + k0 + 32 + sc * 8);
            #pragma unroll
            for (int j = 0; j < NBJ; ++j)
                br[j] = *(const bf16x8*)(Wt + (long)(wrow0 + srow + 64 * j) * K + k0 + 32 + sc * 8);
        }

        bf16x8 af[4], bfv[NF];
        #pragma unroll
        for (int s = 0; s < 4; ++s)
            af[s] = *(const bf16x8*)(&As[(wm + s * 16 + lm) * 40 + chkg * 8]);
        #pragma unroll
        for (int u = 0; u < NF; ++u)
            bfv[u] = *(const bf16x8*)(&Bs[(wn + u * 16 + lm) * 40 + chkg * 8]);
        #pragma unroll
        for (int s = 0; s < 4; ++s)
            #pragma unroll
            for (int u = 0; u < NF; ++u)
                acc[s][u] = MFMA16(af[s], bfv[u], acc[s][u], 0, 0, 0);
    }

    const int col = lane & 15;
    const int rq  = (lane >> 4) * 4;
    #pragma unroll
    for (int s = 0; s < 4; ++s) {
        #pragma unroll
        for (int u = 0; u < NF; ++u) {
            const int gn = ccol0 + wn + u * 16 + col;
            const float bb = bias[gn];
            #pragma unroll
            for (int r = 0; r < 4; ++r) {
                const int gm = m0 + wm + s * 16 + rq + r;
                float v = acc[s][u][r] + bb;
                if (RELU) v = fmaxf(v, 0.f);
                if (OMODE == 0) {
                    Cf[(long)gm * ldc + gn] = v;
                } else if (OMODE == 1) {
                    Cb[(long)gm * ldc + gn] = f2bf(v);
                } else {
                    const int n   = gm / LEN;
                    const int pix = gm - n * LEN;
                    const int h   = gn >> 5, d = gn & 31;
                    Cb[((long)(n * NH + h) * LEN + pix) * 32 + d] = f2bf(v);
                }
            }
        }
    }
}

template <int BN, int RELU, int OMODE>
__global__ __launch_bounds__(256) void gemm128(
    const short* __restrict__ A, const short* __restrict__ Wt,
    const float* __restrict__ bias, float* Cf, short* Cb, int ldc, int K)
{
    __shared__ __align__(16) short As[128 * 40];
    __shared__ __align__(16) short Bs[BN * 40];
    gemm_core128<BN, RELU, OMODE>(As, Bs, A, Wt, bias, Cf, Cb, ldc,
                                  blockIdx.y * 128, blockIdx.x * BN,
                                  blockIdx.x * BN, K);
}

// Fused query-side GEMM: [Vb | OFF | AW] over N=640 (Wv|Woff|Wa rows contiguous).
__global__ __launch_bounds__(256) void gemm_qkv128(
    const short* __restrict__ curb, const short* __restrict__ qb,
    const short* __restrict__ Wt, const float* __restrict__ bv,
    const float* __restrict__ boff, const float* __restrict__ ba,
    short* __restrict__ Vb, float* __restrict__ OFF, float* __restrict__ AW)
{
    __shared__ __align__(16) short As[128 * 40];
    __shared__ __align__(16) short Bs[128 * 40];
    const int n0 = blockIdx.x * 128;   // 0,128,256,384,512
    if (n0 < 256) {
        gemm_core128<128, 0, 2>(As, Bs, curb, Wt, bv, (float*)nullptr, Vb,
                                256, blockIdx.y * 128, n0, n0, 256);
    } else if (n0 < 512) {
        gemm_core128<128, 0, 0>(As, Bs, qb, Wt, boff, OFF, (short*)nullptr,
                                256, blockIdx.y * 128, n0, n0 - 256, 256);
    } else {
        gemm_core128<128, 0, 0>(As, Bs, qb, Wt, ba, AW, (short*)nullptr,
                                128, blockIdx.y * 128, n0, n0 - 512, 256);
    }
}

// ---------------------------------------------------------------------------
// Fused GEMM + residual(bf16) + LayerNorm (R7 M32 structure, grid 340).
// Wave w: rows (w&1)*16..+16, cols (w>>1)*128..+128 (1x8 subtiles).
// Resid fragment PREFETCHED into registers before the K-loop (independent
// load, overlaps MFMA). All trunk I/O bf16; f32 only for final d_out.
// ---------------------------------------------------------------------------
template <int K>
__global__ __launch_bounds__(256) void gemm_ln(
    const short* __restrict__ A, const short* __restrict__ Wt,
    const float* __restrict__ bias, const short* __restrict__ residb,
    const float* __restrict__ g, const float* __restrict__ be,
    short* __restrict__ outb, short* __restrict__ outq,
    float* __restrict__ outf, const float* __restrict__ pos)
{
    __shared__ __align__(16) short As[32 * 40];
    __shared__ __align__(16) short Bs[256 * 40];
    __shared__ float red[2][32][2];

    const int t    = threadIdx.x;
    const int wave = t >> 6, lane = t & 63;
    const int wm   = (wave & 1) * 16;
    const int wn   = (wave >> 1) * 128;
    const int lm   = lane & 15;
    const int chkg = lane >> 4;
    const int rq   = chkg * 4;
    const int srow = t >> 2;          // 0..63
    const int sc   = t & 3;
    const int m0   = blockIdx.x * 32;
    const bool doA = (t < 128);       // wave-uniform (waves 0,1)

    // ---- resid prefetch (independent of K-loop) ----
    short rr[8][4];
    #pragma unroll
    for (int u = 0; u < 8; ++u)
        #pragma unroll
        for (int r = 0; r < 4; ++r)
            rr[u][r] = residb[(long)(m0 + wm + rq + r) * DM + wn + u * 16 + lm];

    f32x4 acc[8] = {};
    bf16x8 ar, br[4];

    if (doA) ar = *(const bf16x8*)(A + (long)(m0 + srow) * K + sc * 8);
    #pragma unroll
    for (int j = 0; j < 4; ++j)
        br[j] = *(const bf16x8*)(Wt + (long)(srow + 64 * j) * K + sc * 8);

    for (int k0 = 0; k0 < K; k0 += 32) {
        __syncthreads();
        if (doA) *(bf16x8*)(&As[srow * 40 + sc * 8]) = ar;
        #pragma unroll
        for (int j = 0; j < 4; ++j)
            *(bf16x8*)(&Bs[(srow + 64 * j) * 40 + sc * 8]) = br[j];
        __syncthreads();

        if (k0 + 32 < K) {
            if (doA) ar = *(const bf16x8*)(A + (long)(m0 + srow) * K + k0 + 32 + sc * 8);
            #pragma unroll
            for (int j = 0; j < 4; ++j)
                br[j] = *(const bf16x8*)(Wt + (long)(srow + 64 * j) * K + k0 + 32 + sc * 8);
        }

        bf16x8 af = *(const bf16x8*)(&As[(wm + lm) * 40 + chkg * 8]);
        #pragma unroll
        for (int u = 0; u < 8; ++u) {
            bf16x8 bfv = *(const bf16x8*)(&Bs[(wn + u * 16 + lm) * 40 + chkg * 8]);
            acc[u] = MFMA16(af, bfv, acc[u], 0, 0, 0);
        }
    }

    // ---- epilogue: v = acc + bias + resid(bf16) ----
    #pragma unroll
    for (int u = 0; u < 8; ++u) {
        const int gn = wn + u * 16 + lm;
        const float bb = bias[gn];
        #pragma unroll
        for (int r = 0; r < 4; ++r)
            acc[u][r] += bb + bf2f(rr[u][r]);
    }

    float rs[4], r2[4];
    #pragma unroll
    for (int r = 0; r < 4; ++r) {
        float s = 0.f, s2 = 0.f;
        #pragma unroll
        for (int u = 0; u < 8; ++u) { const float v = acc[u][r]; s += v; s2 += v * v; }
        rs[r] = s; r2[r] = s2;
    }
    #pragma unroll
    for (int o = 1; o < 16; o <<= 1)
        #pragma unroll
        for (int r = 0; r < 4; ++r) {
            rs[r] += __shfl_xor(rs[r], o, 64);
            r2[r] += __shfl_xor(r2[r], o, 64);
        }
    if (lm == 0) {
        #pragma unroll
        for (int r = 0; r < 4; ++r) {
            red[wave >> 1][wm + rq + r][0] = rs[r];
            red[wave >> 1][wm + rq + r][1] = r2[r];
        }
    }
    __syncthreads();
    #pragma unroll
    for (int r = 0; r < 4; ++r) {
        const int row = wm + rq + r;
        const float ts = red[0][row][0] + red[1][row][0];
        const float t2 = red[0][row][1] + red[1][row][1];
        const float mean = ts * (1.f / DM);
        const float var  = t2 * (1.f / DM) - mean * mean;
        rs[r] = mean;
        r2[r] = rsqrtf(var + 1e-5f);
    }
    #pragma unroll
    for (int u = 0; u < 8; ++u) {
        const int gn = wn + u * 16 + lm;
        const float gg = g[gn], bbe = be[gn];
        #pragma unroll
        for (int r = 0; r < 4; ++r) {
            const long gm = m0 + wm + rq + r;
            const float o = (acc[u][r] - rs[r]) * r2[r] * gg + bbe;
            if (outb) outb[gm * DM + gn] = f2bf(o);
            if (outq) outq[gm * DM + gn] = f2bf(o + pos[gm * DM + gn]);
            if (outf) outf[gm * DM + gn] = o;
        }
    }
}

// ---------------------------------------------------------------------------
// Deformable attention sampling v3 (unchanged).
// ---------------------------------------------------------------------------
__global__ __launch_bounds__(256) void deform_attn_v3(
    const short* __restrict__ Vb,    // (NB*NH, LEN, 32) bf16
    const float* __restrict__ OFF,   // (MROWS, 256)
    const float* __restrict__ AW,    // (MROWS, 128)
    const float* __restrict__ vr,    // (NB, NLV, 2)
    bf16x4* __restrict__ ATTb)       // (MROWS, 64) bf16x4
{
    const int starts[5] = {0, 4096, 5120, 5376, 5440};
    const int dims[4]   = {64, 32, 16, 8};

    const int wave = threadIdx.x >> 6;
    const int lane = threadIdx.x & 63;
    const int h    = lane >> 3;
    const int d4   = lane & 7;

    const int gq = blockIdx.x * 4 + wave;
    const int n  = gq / LEN;
    const int q  = gq % LEN;

    int lq = 3;
    if (q < 4096) lq = 0; else if (q < 5120) lq = 1; else if (q < 5376) lq = 2;
    const int r  = q - starts[lq];
    const int Wq = dims[lq];
    const int gy = r / Wq, gx = r % Wq;
    const float vrxq = vr[(n * NLV + lq) * 2 + 0];
    const float vryq = vr[(n * NLV + lq) * 2 + 1];
    const float rx = (gx + 0.5f) / (vrxq * Wq);
    const float ry = (gy + 0.5f) / (vryq * Wq);

    const long row = (long)n * LEN + q;

    const float* awp = AW + row * 128 + h * 16;
    float a[16];
    float mx = -1e30f;
    #pragma unroll
    for (int i = 0; i < 16; ++i) { a[i] = awp[i]; mx = fmaxf(mx, a[i]); }
    float s = 0.f;
    #pragma unroll
    for (int i = 0; i < 16; ++i) { a[i] = __expf(a[i] - mx); s += a[i]; }
    const float inv = 1.f / s;

    const float* offp = OFF + row * 256 + h * 32;

    float4 acc = {0.f, 0.f, 0.f, 0.f};
    #pragma unroll
    for (int lvl = 0; lvl < NLV; ++lvl) {
        const int Hl = dims[lvl];
        const int Wl = Hl;
        const float fW = (float)Wl;
        const int sb = starts[lvl];
        const float lx = rx * vr[(n * NLV + lvl) * 2 + 0];
        const float ly = ry * vr[(n * NLV + lvl) * 2 + 1];
        const short* vb = Vb + ((long)(n * NH + h) * LEN + sb) * 32 + d4 * 4;
        #pragma unroll
        for (int p = 0; p < NPT; ++p) {
            const float ox = offp[lvl * 8 + p * 2 + 0];
            const float oy = offp[lvl * 8 + p * 2 + 1];
            const float x = fmaf(lx, fW, ox) - 0.5f;
            const float y = fmaf(ly, fW, oy) - 0.5f;
            const float x0f = floorf(x), y0f = floorf(y);
            const int ix0 = (int)x0f, iy0 = (int)y0f;
            const float wx1 = x - x0f, wy1 = y - y0f;
            const float wx0 = 1.f - wx1, wy0 = 1.f - wy1;

            const bool vx0 = (ix0 >= 0)     && (ix0 < Wl);
            const bool vx1 = (ix0 + 1 >= 0) && (ix0 + 1 < Wl);
            const bool vy0 = (iy0 >= 0)     && (iy0 < Hl);
            const bool vy1 = (iy0 + 1 >= 0) && (iy0 + 1 < Hl);
            const int cx0 = min(max(ix0, 0), Wl - 1);
            const int cx1 = min(max(ix0 + 1, 0), Wl - 1);
            const int cy0 = min(max(iy0, 0), Hl - 1);
            const int cy1 = min(max(iy0 + 1, 0), Hl - 1);

            const float w00 = (vx0 && vy0) ? wx0 * wy0 : 0.f;
            const float w10 = (vx1 && vy0) ? wx1 * wy0 : 0.f;
            const float w01 = (vx0 && vy1) ? wx0 * wy1 : 0.f;
            const float w11 = (vx1 && vy1) ? wx1 * wy1 : 0.f;

            const bf16x4 g00 = *(const bf16x4*)(vb + (long)(cy0 * Wl + cx0) * 32);
            const bf16x4 g10 = *(const bf16x4*)(vb + (long)(cy0 * Wl + cx1) * 32);
            const bf16x4 g01 = *(const bf16x4*)(vb + (long)(cy1 * Wl + cx0) * 32);
            const bf16x4 g11 = *(const bf16x4*)(vb + (long)(cy1 * Wl + cx1) * 32);

            const float awv = a[lvl * 4 + p] * inv;
            #pragma unroll
            for (int e = 0; e < 4; ++e) {
                float sv = w00 * bf2f(g00[e]) + w10 * bf2f(g10[e])
                         + w01 * bf2f(g01[e]) + w11 * bf2f(g11[e]);
                (&acc.x)[e] += awv * sv;
            }
        }
    }
    bf16x4 ob;
    ob[0] = f2bf(acc.x); ob[1] = f2bf(acc.y);
    ob[2] = f2bf(acc.z); ob[3] = f2bf(acc.w);
    ATTb[row * 64 + h * 8 + d4] = ob;
}

// ---------------------------------------------------------------------------
extern "C" void kernel_launch(void* const* d_in, const int* in_sizes, int n_in,
                              void* d_out, int out_size, void* d_ws, size_t ws_size,
                              hipStream_t stream)
{
    const float* src = (const float*)d_in[0];
    const float* pos = (const float*)d_in[1];
    const float* vr  = (const float*)d_in[2];
    const float* Wv_   = (const float*)d_in[3];
    const float* bv_   = (const float*)d_in[4];
    const float* Woff_ = (const float*)d_in[5];
    const float* boff_ = (const float*)d_in[6];
    const float* Wa_   = (const float*)d_in[7];
    const float* ba_   = (const float*)d_in[8];
    const float* Wo_   = (const float*)d_in[9];
    const float* bo_   = (const float*)d_in[10];
    const float* g1_   = (const float*)d_in[11];
    const float* be1_  = (const float*)d_in[12];
    const float* Wl1_  = (const float*)d_in[13];
    const float* bl1_  = (const float*)d_in[14];
    const float* Wl2_  = (const float*)d_in[15];
    const float* bl2_  = (const float*)d_in[16];
    const float* g2_   = (const float*)d_in[17];
    const float* be2_  = (const float*)d_in[18];

    const long SZ = (long)MROWS * DM;        // 2,785,280 elements
    float* ws = (float*)d_ws;
    float* OFF  = ws;                         // f32 M x 256
    float* AW   = OFF + SZ;                   // f32 M x 128
    short* Vb   = (short*)(AW + (long)MROWS * 128);  // bf16 (NB*NH, LEN, 32)
    short* curb = Vb   + SZ;                  // bf16 M x 256 (trunk)
    short* qb   = curb + SZ;                  // bf16 M x 256 (trunk + pos)
    short* ATTb = qb   + SZ;                  // bf16 M x 256
    short* XAb  = ATTb + SZ;                  // bf16 M x 256 (LN1 out)
    short* FFNb = XAb  + SZ;                  // bf16 M x 1024
    short* Wt   = FFNb + (long)MROWS * DFFN;  // 2 x 753664 bf16 weights

    const dim3 blk(256);
    const int GYM = MROWS / 128;              // 85
    const int GLN = MROWS / 32;               // 340

    hipLaunchKernelGGL(transpose_convert_all, dim3(1472), blk, 0, stream,
                       Wv_, Woff_, Wa_, Wo_, Wl1_, Wl2_, Wt);
    hipLaunchKernelGGL(convert_src, dim3(SZ / 4 / 256), blk, 0, stream,
                       (const float4*)src, (const float4*)pos,
                       (bf16x4*)curb, (bf16x4*)qb);

    for (int l = 0; l < 2; ++l) {
        const short* Wbase = Wt + (long)l * 753664;
        const float* bv   = bv_   + (long)l * DM;
        const float* boff = boff_ + (long)l * 256;
        const float* ba   = ba_   + (long)l * 128;
        const float* bo   = bo_   + (long)l * DM;
        const float* g1   = g1_   + (long)l * DM;
        const float* be1  = be1_  + (long)l * DM;
        const float* bl1  = bl1_  + (long)l * DFFN;
        const float* bl2  = bl2_  + (long)l * DM;
        const float* g2   = g2_   + (long)l * DM;
        const float* be2  = be2_  + (long)l * DM;

        // [Vb | OFF | AW] = [curb | qb] @ [Wv|Woff|Wa]   (BN=128, 5x85)
        hipLaunchKernelGGL(gemm_qkv128, dim3(5, GYM), blk, 0, stream,
                           curb, qb, Wbase, bv, boff, ba, Vb, OFF, AW);
        hipLaunchKernelGGL(deform_attn_v3, dim3(MROWS / 4), blk, 0, stream,
                           Vb, OFF, AW, vr, (bf16x4*)ATTb);
        // XAb = bf16( LN(curb + ATT@Wo + bo) )
        hipLaunchKernelGGL((gemm_ln<256>), dim3(GLN), blk, 0, stream,
                           ATTb, Wbase + 163840, bo, curb, g1, be1,
                           XAb, (short*)nullptr, (float*)nullptr,
                           (const float*)nullptr);
        // FFNb = relu(XAb @ Wl1 + bl1)  bf16 out  (BN=128, 8x85)
        hipLaunchKernelGGL((gemm128<128, 1, 1>), dim3(8, GYM), blk, 0, stream,
                           XAb, Wbase + 229376, bl1, (float*)nullptr, FFNb, 1024, 256);
        // LN2: layer0 -> curb (trunk) + qb (trunk+pos); layer1 -> d_out f32
        if (l == 0) {
            hipLaunchKernelGGL((gemm_ln<1024>), dim3(GLN), blk, 0, stream,
                               FFNb, Wbase + 491520, bl2, XAb, g2, be2,
                               curb, qb, (float*)nullptr, pos);
        } else {
            hipLaunchKernelGGL((gemm_ln<1024>), dim3(GLN), blk, 0, stream,
                               FFNb, Wbase + 491520, bl2, XAb, g2, be2,
                               (short*)nullptr, (short*)nullptr,
                               (float*)d_out, (const float*)nullptr);
        }
    }
}